// Round 1
// baseline (49.734 us; speedup 1.0000x reference)
//
#include <hip/hip_runtime.h>
#include <math.h>

namespace {
constexpr int GD = 64;
constexpr int GK = 32;
constexpr float LOG2PI_F = 1.8378770664093454f;

// Kernel 1: fold theta -> w1[K*D], w2[K*D], A[K] in ws; priors -> out[0].
__global__ __launch_bounds__(256) void gmm_prep(const float* __restrict__ theta,
                                                float* __restrict__ ws,
                                                float* __restrict__ out) {
  const int t = threadIdx.x;
  const int k = t >> 3;   // 0..31
  const int jj = t & 7;   // 8 threads per component
  float s_ls = 0.f, s_m2 = 0.f, pr = 0.f;
#pragma unroll
  for (int i = 0; i < 8; ++i) {
    const int d = jj * 8 + i;
    const int idx = k * GD + d;
    const float mu = theta[GK + idx];
    const float sg = theta[GK + GK * GD + idx];
    const float iv = 1.0f / (sg * sg);
    const float ls = logf(sg);
    ws[idx] = mu * iv;               // w1 = mu * inv_var
    ws[GK * GD + idx] = -0.5f * iv;  // w2 = -0.5 * inv_var
    s_ls += ls;
    s_m2 += mu * mu * iv;
    // prior_mu elem (-0.5 mu^2 - 0.5 L2P) + prior_sigma elem (-ls - 0.5 L2P - 0.5 ls^2)
    pr += -0.5f * mu * mu - ls - 0.5f * ls * ls - LOG2PI_F;
  }
  // reduce the per-k sums across the 8 lanes that share k (groups lie within a wave)
#pragma unroll
  for (int off = 1; off < 8; off <<= 1) {
    s_ls += __shfl_xor(s_ls, off);
    s_m2 += __shfl_xor(s_m2, off);
  }
  if (jj == 0) {
    const float logp = logf(theta[k]);
    ws[2 * GK * GD + k] = logp - s_ls - 0.5f * GD * LOG2PI_F - 0.5f * s_m2;  // A[k]
    pr += 999.0f * logp;  // (ALPHA0 - 1) * log p[k]
  }
  __shared__ float red[256];
  red[t] = pr;
  __syncthreads();
  for (int off = 128; off > 0; off >>= 1) {
    if (t < off) red[t] += red[t + off];
    __syncthreads();
  }
  if (t == 0) {
    // gammaln(K*a) - K*gammaln(a), compile-time-constant shape, runtime lgamma for accuracy
    const double gterm = lgamma(32.0 * 1000.0) - 32.0 * lgamma(1000.0);
    out[0] = red[0] + (float)gterm;
  }
}

// Kernel 2: one thread per row. comp[k] = A[k] + sum_d x*(w1 + x*w2); online LSE over k.
__global__ __launch_bounds__(256) void gmm_main(const float* __restrict__ x,
                                                const float* __restrict__ ws,
                                                const int* __restrict__ fds,
                                                float* __restrict__ out,
                                                int n) {
  const int row = blockIdx.x * 256 + threadIdx.x;
  float lse = 0.0f;
  if (row < n) {
    float4 xr[16];
    const float4* __restrict__ xp = reinterpret_cast<const float4*>(x + (size_t)row * GD);
#pragma unroll
    for (int i = 0; i < 16; ++i) xr[i] = xp[i];
    const float* __restrict__ A = ws + 2 * GK * GD;
    float m = -INFINITY;
    float ssum = 0.0f;
    for (int k = 0; k < GK; ++k) {
      // block-uniform weight addresses -> scalar loads / L1-broadcast (16 KB fits L1)
      const float4* __restrict__ w1k = reinterpret_cast<const float4*>(ws + k * GD);
      const float4* __restrict__ w2k = reinterpret_cast<const float4*>(ws + GK * GD + k * GD);
      float acc0 = 0.f, acc1 = 0.f, acc2 = 0.f, acc3 = 0.f;
#pragma unroll
      for (int i = 0; i < 16; ++i) {  // 4 independent FMA chains for ILP
        const float4 xq = xr[i];
        const float4 p = w1k[i];
        const float4 q = w2k[i];
        acc0 = fmaf(xq.x, fmaf(xq.x, q.x, p.x), acc0);
        acc1 = fmaf(xq.y, fmaf(xq.y, q.y, p.y), acc1);
        acc2 = fmaf(xq.z, fmaf(xq.z, q.z, p.z), acc2);
        acc3 = fmaf(xq.w, fmaf(xq.w, q.w, p.w), acc3);
      }
      const float c = A[k] + ((acc0 + acc1) + (acc2 + acc3));
      const float mn = fmaxf(m, c);
      ssum = ssum * __expf(m - mn) + __expf(c - mn);
      m = mn;
    }
    lse = m + __logf(ssum);
  }
  // block-sum of lse: wave shuffle reduce, then LDS across the 4 waves
  float v = lse;
#pragma unroll
  for (int off = 32; off > 0; off >>= 1) v += __shfl_down(v, off);
  __shared__ float bs[4];
  if ((threadIdx.x & 63) == 0) bs[threadIdx.x >> 6] = v;
  __syncthreads();
  if (threadIdx.x == 0) {
    const float tot = (bs[0] + bs[1]) + (bs[2] + bs[3]);
    const float scale = (float)fds[0] / (float)n;
    atomicAdd(out, tot * scale);
  }
}
}  // namespace

extern "C" void kernel_launch(void* const* d_in, const int* in_sizes, int n_in,
                              void* d_out, int out_size, void* d_ws, size_t ws_size,
                              hipStream_t stream) {
  const float* x = (const float*)d_in[0];
  const float* theta = (const float*)d_in[1];
  const int* fds = (const int*)d_in[2];
  float* out = (float*)d_out;
  float* ws = (float*)d_ws;
  const int n = in_sizes[0] / GD;  // 50000

  gmm_prep<<<1, 256, 0, stream>>>(theta, ws, out);
  const int nb = (n + 255) / 256;
  gmm_main<<<nb, 256, 0, stream>>>(x, ws, fds, out, n);
}

// Round 2
// 28.554 us; speedup vs baseline: 1.7417x; 1.7417x over previous
//
#include <hip/hip_runtime.h>
#include <math.h>

namespace {
constexpr int GD = 64;
constexpr int GK = 32;
constexpr float LOG2PI_F = 1.8378770664093454f;

__device__ __forceinline__ float4 v4fma(const float4 a, const float4 b, float4 c) {
  c.x = fmaf(a.x, b.x, c.x);
  c.y = fmaf(a.y, b.y, c.y);
  c.z = fmaf(a.z, b.z, c.z);
  c.w = fmaf(a.w, b.w, c.w);
  return c;
}
__device__ __forceinline__ float4 v4sq(const float4 a) {
  return make_float4(a.x * a.x, a.y * a.y, a.z * a.z, a.w * a.w);
}

// One fused kernel. Each block:
//   1) folds theta -> w1 = mu*iv, w2 = -0.5*iv, A[k] into its own LDS (block 0 also
//      wave-reduces the priors),
//   2) computes rows: 4 lanes per row (q = tid&3 owns 16 dims), x+x^2 in registers,
//      per-k dot via LDS weights + 2 shfl_xor, split logsumexp (8 exps/lane),
//   3) block-reduces and atomicAdds into out (pre-zeroed by hipMemsetAsync).
__global__ __launch_bounds__(256) void gmm_fused(const float* __restrict__ x,
                                                 const float* __restrict__ theta,
                                                 const int* __restrict__ fds,
                                                 float* __restrict__ out,
                                                 int n) {
  __shared__ float w1s[GK * GD];
  __shared__ float w2s[GK * GD];
  __shared__ float As[GK];
  __shared__ float pred[4];  // priors, per-wave partials
  __shared__ float bred[4];  // lse block sum, per-wave partials

  const int t = threadIdx.x;

  // ---- prep: every block folds theta into LDS ----
  {
    const int k = t >> 3;   // 0..31
    const int jj = t & 7;   // 8 lanes per component
    float s_ls = 0.f, s_m2 = 0.f, pr = 0.f;
#pragma unroll
    for (int i = 0; i < 8; ++i) {
      const int idx = k * GD + jj * 8 + i;
      const float mu = theta[GK + idx];
      const float sg = theta[GK + GK * GD + idx];
      const float iv = 1.0f / (sg * sg);
      const float ls = __logf(sg);
      w1s[idx] = mu * iv;
      w2s[idx] = -0.5f * iv;
      s_ls += ls;
      s_m2 += mu * mu * iv;
      // prior_mu + prior_sigma element terms
      pr += -0.5f * mu * mu - ls - 0.5f * ls * ls - LOG2PI_F;
    }
#pragma unroll
    for (int off = 1; off < 8; off <<= 1) {
      s_ls += __shfl_xor(s_ls, off);
      s_m2 += __shfl_xor(s_m2, off);
    }
    if (jj == 0) {
      const float logp = __logf(theta[k]);
      As[k] = logp - s_ls - 0.5f * GD * LOG2PI_F - 0.5f * s_m2;
      pr += 999.0f * logp;  // (ALPHA0-1) * log p
    }
#pragma unroll
    for (int off = 1; off < 64; off <<= 1) pr += __shfl_xor(pr, off);
    if ((t & 63) == 0) pred[t >> 6] = pr;
  }
  __syncthreads();

  // ---- main: 4 lanes per row ----
  const int q = t & 3;
  const int row = (blockIdx.x * 256 + t) >> 2;
  float lse = 0.0f;
  if (row < n) {
    const float4* __restrict__ xp =
        reinterpret_cast<const float4*>(x + (size_t)row * GD + q * 16);
    const float4 xa0 = xp[0], xa1 = xp[1], xa2 = xp[2], xa3 = xp[3];
    const float4 xb0 = v4sq(xa0), xb1 = v4sq(xa1), xb2 = v4sq(xa2), xb3 = v4sq(xa3);

    const float* __restrict__ w1p = &w1s[q * 16];
    const float* __restrict__ w2p = &w2s[q * 16];
    float ck[8];  // this lane's 8 owned components (static-indexed under full unroll)
#pragma unroll
    for (int k = 0; k < GK; ++k) {
      const float4* w1 = reinterpret_cast<const float4*>(w1p + k * GD);
      const float4* w2 = reinterpret_cast<const float4*>(w2p + k * GD);
      float4 acc = make_float4(0.f, 0.f, 0.f, 0.f);
      acc = v4fma(xa0, w1[0], acc);
      acc = v4fma(xb0, w2[0], acc);
      acc = v4fma(xa1, w1[1], acc);
      acc = v4fma(xb1, w2[1], acc);
      acc = v4fma(xa2, w1[2], acc);
      acc = v4fma(xb2, w2[2], acc);
      acc = v4fma(xa3, w1[3], acc);
      acc = v4fma(xb3, w2[3], acc);
      float part = (acc.x + acc.y) + (acc.z + acc.w);
      part += __shfl_xor(part, 1);
      part += __shfl_xor(part, 2);
      const float c = As[k] + part;
      if ((k >> 3) == q) ck[k & 7] = c;  // k>>3, k&7 compile-time constants
    }
    // split logsumexp: each lane reduces its 8, then combine across the 4 lanes
    float m0 = fmaxf(fmaxf(ck[0], ck[1]), fmaxf(ck[2], ck[3]));
    float m1 = fmaxf(fmaxf(ck[4], ck[5]), fmaxf(ck[6], ck[7]));
    float m = fmaxf(m0, m1);
    m = fmaxf(m, __shfl_xor(m, 1));
    m = fmaxf(m, __shfl_xor(m, 2));
    float s0 = __expf(ck[0] - m) + __expf(ck[2] - m) + __expf(ck[4] - m) + __expf(ck[6] - m);
    float s1 = __expf(ck[1] - m) + __expf(ck[3] - m) + __expf(ck[5] - m) + __expf(ck[7] - m);
    float s = (s0 + s1);
    s += __shfl_xor(s, 1);
    s += __shfl_xor(s, 2);
    lse = (q == 0) ? (m + __logf(s)) : 0.0f;
  }

  // ---- block reduction + output ----
  float v = lse;
#pragma unroll
  for (int off = 32; off > 0; off >>= 1) v += __shfl_xor(v, off);
  if ((t & 63) == 0) bred[t >> 6] = v;
  __syncthreads();
  if (t == 0) {
    float acc = ((bred[0] + bred[1]) + (bred[2] + bred[3])) *
                ((float)fds[0] / (float)n);
    if (blockIdx.x == 0) {
      const double gterm = lgamma(32.0 * 1000.0) - 32.0 * lgamma(1000.0);
      acc += (pred[0] + pred[1]) + (pred[2] + pred[3]) + (float)gterm;
    }
    atomicAdd(out, acc);
  }
}
}  // namespace

extern "C" void kernel_launch(void* const* d_in, const int* in_sizes, int n_in,
                              void* d_out, int out_size, void* d_ws, size_t ws_size,
                              hipStream_t stream) {
  const float* x = (const float*)d_in[0];
  const float* theta = (const float*)d_in[1];
  const int* fds = (const int*)d_in[2];
  float* out = (float*)d_out;
  const int n = in_sizes[0] / GD;  // 50000

  hipMemsetAsync(out, 0, sizeof(float) * (size_t)out_size, stream);
  const int nb = (n * 4 + 255) / 256;  // 4 lanes per row
  gmm_fused<<<nb, 256, 0, stream>>>(x, theta, fds, out, n);
}

// Round 3
// 22.633 us; speedup vs baseline: 2.1974x; 1.2616x over previous
//
#include <hip/hip_runtime.h>
#include <math.h>

namespace {
constexpr int GD = 64;
constexpr int GK = 32;
constexpr float LOG2PI_F = 1.8378770664093454f;

typedef __attribute__((ext_vector_type(8))) short bf16x8;
typedef __attribute__((ext_vector_type(4))) float f32x4;

__device__ __forceinline__ short f2bf(float f) {
  union { float f; unsigned u; } v;
  v.f = f;
  const unsigned r = v.u + 0x7fffu + ((v.u >> 16) & 1u);  // RNE
  return (short)(r >> 16);
}

__device__ __forceinline__ float4 sq4(const float4 a) {
  return make_float4(a.x * a.x, a.y * a.y, a.z * a.z, a.w * a.w);
}

__device__ __forceinline__ bf16x8 pack8(const float4 a, const float4 b) {
  bf16x8 r;
  r[0] = f2bf(a.x); r[1] = f2bf(a.y); r[2] = f2bf(a.z); r[3] = f2bf(a.w);
  r[4] = f2bf(b.x); r[5] = f2bf(b.y); r[6] = f2bf(b.z); r[7] = f2bf(b.w);
  return r;
}

// Wave = one 16-row tile. Features F=128 = [x(64), x^2(64)], K-steps s=0..3 (32 each).
// A-frag (16x32 bf16): lane l holds row l&15, k = (l>>4)*8 + j  (verified layout, m92 ladder).
// B-frag (32x16 bf16): lane l holds col l&15, k = (l>>4)*8 + j  -> weights held in VGPRs.
// D (f32x4): col = lane&15, row = (lane>>4)*4 + reg (m89-verified).
__global__ __launch_bounds__(256) void gmm_main(const float* __restrict__ x,
                                                const float* __restrict__ theta,
                                                float* __restrict__ ws, int n) {
  const int t = threadIdx.x;
  const int lane = t & 63;
  const int wave = t >> 6;
  const int c1 = lane & 15;   // col (component) for D0; c1+16 for D1
  const int g = lane >> 4;    // k-group
  const int dA = g * 8;       // x dims for s=0 (and x^2 for s=2)
  const int dB = 32 + g * 8;  // x dims for s=1 (and x^2 for s=3)

  // ---- issue x loads first so global latency overlaps the weight fold ----
  const int rowbase = blockIdx.x * 64 + wave * 16;
  int lr = rowbase + c1;
  if (lr > n - 1) lr = n - 1;  // clamp loads; masked at the sum
  const float* __restrict__ xr = x + (size_t)lr * GD;
  const float4 xa0 = *(const float4*)(xr + dA);
  const float4 xa1 = *(const float4*)(xr + dA + 4);
  const float4 xb0 = *(const float4*)(xr + dB);
  const float4 xb1 = *(const float4*)(xr + dB + 4);

  // ---- fold theta -> register B-fragments + per-col LSE constants As ----
  bf16x8 w1A[2], w1B[2], w2A[2], w2B[2];  // [h]: h=0 -> col c1, h=1 -> col c1+16
  float As[2];
#pragma unroll
  for (int h = 0; h < 2; ++h) {
    const int c = c1 + h * 16;
    const float* __restrict__ mu = theta + GK + c * GD;
    const float* __restrict__ sg = theta + GK + GK * GD + c * GD;
    const float4 m0 = *(const float4*)(mu + dA), m1 = *(const float4*)(mu + dA + 4);
    const float4 m2v = *(const float4*)(mu + dB), m3 = *(const float4*)(mu + dB + 4);
    const float4 s0 = *(const float4*)(sg + dA), s1 = *(const float4*)(sg + dA + 4);
    const float4 s2v = *(const float4*)(sg + dB), s3 = *(const float4*)(sg + dB + 4);
    const float mv[16] = {m0.x, m0.y, m0.z, m0.w, m1.x, m1.y, m1.z, m1.w,
                          m2v.x, m2v.y, m2v.z, m2v.w, m3.x, m3.y, m3.z, m3.w};
    const float sv[16] = {s0.x, s0.y, s0.z, s0.w, s1.x, s1.y, s1.z, s1.w,
                          s2v.x, s2v.y, s2v.z, s2v.w, s3.x, s3.y, s3.z, s3.w};
    float ls = 0.f, mm = 0.f;
#pragma unroll
    for (int j = 0; j < 16; ++j) {
      const float iv = 1.0f / (sv[j] * sv[j]);
      const float l = __logf(sv[j]);
      ls += l;
      mm = fmaf(mv[j] * mv[j], iv, mm);
      const short b1 = f2bf(mv[j] * iv);    // w1 = mu * inv_var
      const short b2 = f2bf(-0.5f * iv);    // w2 = -0.5 * inv_var
      if (j < 8) { w1A[h][j] = b1; w2A[h][j] = b2; }
      else       { w1B[h][j - 8] = b1; w2B[h][j - 8] = b2; }
    }
    // this lane covers 16 of the 64 dims of col c; 4 g-lanes together cover all 64
    ls += __shfl_xor(ls, 16); ls += __shfl_xor(ls, 32);
    mm += __shfl_xor(mm, 16); mm += __shfl_xor(mm, 32);
    As[h] = __logf(theta[c]) - ls - 0.5f * GD * LOG2PI_F - 0.5f * mm;
  }

  // ---- A-fragments and the 8 MFMAs ----
  const bf16x8 a0 = pack8(xa0, xa1);            // s=0: x  @ dA
  const bf16x8 a1 = pack8(xb0, xb1);            // s=1: x  @ dB
  const bf16x8 a2 = pack8(sq4(xa0), sq4(xa1));  // s=2: x^2@ dA
  const bf16x8 a3 = pack8(sq4(xb0), sq4(xb1));  // s=3: x^2@ dB
  f32x4 D0 = {0.f, 0.f, 0.f, 0.f};
  f32x4 D1 = {0.f, 0.f, 0.f, 0.f};
  D0 = __builtin_amdgcn_mfma_f32_16x16x32_bf16(a0, w1A[0], D0, 0, 0, 0);
  D1 = __builtin_amdgcn_mfma_f32_16x16x32_bf16(a0, w1A[1], D1, 0, 0, 0);
  D0 = __builtin_amdgcn_mfma_f32_16x16x32_bf16(a1, w1B[0], D0, 0, 0, 0);
  D1 = __builtin_amdgcn_mfma_f32_16x16x32_bf16(a1, w1B[1], D1, 0, 0, 0);
  D0 = __builtin_amdgcn_mfma_f32_16x16x32_bf16(a2, w2A[0], D0, 0, 0, 0);
  D1 = __builtin_amdgcn_mfma_f32_16x16x32_bf16(a2, w2A[1], D1, 0, 0, 0);
  D0 = __builtin_amdgcn_mfma_f32_16x16x32_bf16(a3, w2B[0], D0, 0, 0, 0);
  D1 = __builtin_amdgcn_mfma_f32_16x16x32_bf16(a3, w2B[1], D1, 0, 0, 0);

  // ---- LSE across the 16 col-lanes (4 rows per lane in D regs) ----
  float rowsum = 0.f;
#pragma unroll
  for (int j = 0; j < 4; ++j) {
    const float cc0 = D0[j] + As[0];
    const float cc1 = D1[j] + As[1];
    float m = fmaxf(cc0, cc1);
    m = fmaxf(m, __shfl_xor(m, 1));
    m = fmaxf(m, __shfl_xor(m, 2));
    m = fmaxf(m, __shfl_xor(m, 4));
    m = fmaxf(m, __shfl_xor(m, 8));
    float e = __expf(cc0 - m) + __expf(cc1 - m);
    e += __shfl_xor(e, 1);
    e += __shfl_xor(e, 2);
    e += __shfl_xor(e, 4);
    e += __shfl_xor(e, 8);
    const int rj = rowbase + g * 4 + j;  // D row = (lane>>4)*4 + reg
    const float lse = m + __logf(e);
    rowsum += (rj < n) ? lse : 0.f;
  }
  float v = (c1 == 0) ? rowsum : 0.f;  // one lane per (g, row-quad)
  v += __shfl_xor(v, 16);
  v += __shfl_xor(v, 32);
  __shared__ float bred[4];
  if (lane == 0) bred[wave] = v;
  __syncthreads();
  if (t == 0) ws[blockIdx.x] = (bred[0] + bred[1]) + (bred[2] + bred[3]);
}

// 1-block tail: sum per-block partials, scale, add all priors, overwrite out.
__global__ __launch_bounds__(256) void gmm_tail(const float* __restrict__ theta,
                                                const int* __restrict__ fds,
                                                const float* __restrict__ ws,
                                                float* __restrict__ out,
                                                int n, int nblk) {
  const int t = threadIdx.x;
  float acc = 0.f;
  for (int i = t; i < nblk; i += 256) acc += ws[i];
  acc *= (float)fds[0] / (float)n;
  // mu/sigma priors: 2048 elements, 8 per thread
  const int k = t >> 3, jj = t & 7;
  float pr = 0.f;
#pragma unroll
  for (int i = 0; i < 8; ++i) {
    const int idx = k * GD + jj * 8 + i;
    const float mu = theta[GK + idx];
    const float sg = theta[GK + GK * GD + idx];
    const float ls = __logf(sg);
    pr += -0.5f * mu * mu - ls - 0.5f * ls * ls - LOG2PI_F;
  }
  if (jj == 0) pr += 999.0f * __logf(theta[k]);  // (ALPHA0-1)*log p
  acc += pr;
  __shared__ float red[256];
  red[t] = acc;
  __syncthreads();
  for (int off = 128; off > 0; off >>= 1) {
    if (t < off) red[t] += red[t + off];
    __syncthreads();
  }
  if (t == 0) {
    const double gterm = lgamma(32.0 * 1000.0) - 32.0 * lgamma(1000.0);
    out[0] = red[0] + (float)gterm;
  }
}
}  // namespace

extern "C" void kernel_launch(void* const* d_in, const int* in_sizes, int n_in,
                              void* d_out, int out_size, void* d_ws, size_t ws_size,
                              hipStream_t stream) {
  const float* x = (const float*)d_in[0];
  const float* theta = (const float*)d_in[1];
  const int* fds = (const int*)d_in[2];
  float* out = (float*)d_out;
  float* ws = (float*)d_ws;
  const int n = in_sizes[0] / GD;        // 50000
  const int nblk = (n + 63) / 64;        // 64 rows per block (4 waves x 16)

  gmm_main<<<nblk, 256, 0, stream>>>(x, theta, ws, n);
  gmm_tail<<<1, 256, 0, stream>>>(theta, fds, ws, out, n, nblk);
}

// Round 4
// 14.999 us; speedup vs baseline: 3.3158x; 1.5090x over previous
//
#include <hip/hip_runtime.h>
#include <hip/hip_bf16.h>
#include <math.h>

namespace {
constexpr int GD = 64;
constexpr int GK = 32;
constexpr float LOG2PI_F = 1.8378770664093454f;

typedef __attribute__((ext_vector_type(8))) short bf16x8;
typedef __attribute__((ext_vector_type(4))) float f32x4;

__device__ __forceinline__ short f2bf(float f) {
  __hip_bfloat16 h = __float2bfloat16(f);  // compiler pairs into v_cvt_pk_bf16_f32
  return __builtin_bit_cast(short, h);
}

__device__ __forceinline__ float4 sq4(const float4 a) {
  return make_float4(a.x * a.x, a.y * a.y, a.z * a.z, a.w * a.w);
}

__device__ __forceinline__ bf16x8 pack8(const float4 a, const float4 b) {
  bf16x8 r;
  r[0] = f2bf(a.x); r[1] = f2bf(a.y); r[2] = f2bf(a.z); r[3] = f2bf(a.w);
  r[4] = f2bf(b.x); r[5] = f2bf(b.y); r[6] = f2bf(b.z); r[7] = f2bf(b.w);
  return r;
}

// Wave = one 16-row tile; features F=128 = [x(64), x^2(64)], 4 K-steps of 32.
// B-fragments are folded ONCE per block by all 256 threads into LDS:
//   frag[s][g][c][j] : s=0,1 -> mu*iv at dims (s*32 + g*8 + j); s=2,3 -> -0.5*iv same dims.
// A-frag: lane l holds row l&15, k=(l>>4)*8+j. D: col=lane&15, row=(lane>>4)*4+reg (m89).
__global__ __launch_bounds__(256) void gmm_main(const float* __restrict__ x,
                                                const float* __restrict__ theta,
                                                float* __restrict__ ws, int n) {
  __shared__ bf16x8 frag[4][4][32];  // 8 KB: [s][g][c]
  __shared__ float pls[8][32];
  __shared__ float pmm[8][32];
  __shared__ float Asm[GK];
  __shared__ float bred[4];

  const int t = threadIdx.x;
  const int lane = t & 63;
  const int wave = t >> 6;
  const int c1 = lane & 15;  // col for D0; c1+16 for D1
  const int g = lane >> 4;   // k-group
  const int dA = g * 8;      // x dims, first half
  const int dB = 32 + g * 8; // x dims, second half

  // ---- issue x loads first; latency hides under the fold ----
  const int rowbase = blockIdx.x * 64 + wave * 16;
  int lr = rowbase + c1;
  if (lr > n - 1) lr = n - 1;  // clamp; masked at the sum
  const float* __restrict__ xr = x + (size_t)lr * GD;
  const float4 xa0 = *(const float4*)(xr + dA);
  const float4 xa1 = *(const float4*)(xr + dA + 4);
  const float4 xb0 = *(const float4*)(xr + dB);
  const float4 xb1 = *(const float4*)(xr + dB + 4);

  // ---- cooperative fold: thread t handles col c = t&31, 8 dims at d0 ----
  {
    const int c = t & 31;
    const int gh = t >> 5;                       // 0..7
    const int gg = gh & 3;
    const int hf = gh >> 2;                      // which 32-dim half
    const int d0 = hf * 32 + gg * 8;
    const float* __restrict__ mu = theta + GK + c * GD + d0;
    const float* __restrict__ sg = theta + GK + GK * GD + c * GD + d0;
    const float4 m0 = *(const float4*)(mu);
    const float4 m1 = *(const float4*)(mu + 4);
    const float4 s0 = *(const float4*)(sg);
    const float4 s1 = *(const float4*)(sg + 4);
    const float mv[8] = {m0.x, m0.y, m0.z, m0.w, m1.x, m1.y, m1.z, m1.w};
    const float sv[8] = {s0.x, s0.y, s0.z, s0.w, s1.x, s1.y, s1.z, s1.w};
    bf16x8 f1, f2;
    float ls = 0.f, mm = 0.f;
#pragma unroll
    for (int j = 0; j < 8; ++j) {
      const float iv = __builtin_amdgcn_rcpf(sv[j] * sv[j]);
      const float l = __logf(sv[j]);
      ls += l;
      mm = fmaf(mv[j] * mv[j], iv, mm);
      f1[j] = f2bf(mv[j] * iv);    // w1 = mu * inv_var
      f2[j] = f2bf(-0.5f * iv);    // w2 = -0.5 * inv_var
    }
    frag[hf][gg][c] = f1;
    frag[hf + 2][gg][c] = f2;
    pls[gh][c] = ls;
    pmm[gh][c] = mm;
  }
  __syncthreads();
  if (t < GK) {
    float ls = 0.f, mm = 0.f;
#pragma unroll
    for (int i = 0; i < 8; ++i) { ls += pls[i][t]; mm += pmm[i][t]; }
    Asm[t] = __logf(theta[t]) - ls - 0.5f * GD * LOG2PI_F - 0.5f * mm;
  }
  __syncthreads();

  // ---- per-lane fragment reads (contiguous 16B/lane, conflict-free) ----
  const bf16x8 w1A0 = frag[0][g][c1];
  const bf16x8 w1A1 = frag[0][g][c1 + 16];
  const bf16x8 w1B0 = frag[1][g][c1];
  const bf16x8 w1B1 = frag[1][g][c1 + 16];
  const bf16x8 w2A0 = frag[2][g][c1];
  const bf16x8 w2A1 = frag[2][g][c1 + 16];
  const bf16x8 w2B0 = frag[3][g][c1];
  const bf16x8 w2B1 = frag[3][g][c1 + 16];
  const float As0 = Asm[c1];
  const float As1 = Asm[c1 + 16];

  // ---- A-fragments + 8 MFMAs ----
  const bf16x8 a0 = pack8(xa0, xa1);            // x   @ dims dA
  const bf16x8 a1 = pack8(xb0, xb1);            // x   @ dims dB
  const bf16x8 a2 = pack8(sq4(xa0), sq4(xa1));  // x^2 @ dims dA
  const bf16x8 a3 = pack8(sq4(xb0), sq4(xb1));  // x^2 @ dims dB
  f32x4 D0 = {0.f, 0.f, 0.f, 0.f};
  f32x4 D1 = {0.f, 0.f, 0.f, 0.f};
  D0 = __builtin_amdgcn_mfma_f32_16x16x32_bf16(a0, w1A0, D0, 0, 0, 0);
  D1 = __builtin_amdgcn_mfma_f32_16x16x32_bf16(a0, w1A1, D1, 0, 0, 0);
  D0 = __builtin_amdgcn_mfma_f32_16x16x32_bf16(a1, w1B0, D0, 0, 0, 0);
  D1 = __builtin_amdgcn_mfma_f32_16x16x32_bf16(a1, w1B1, D1, 0, 0, 0);
  D0 = __builtin_amdgcn_mfma_f32_16x16x32_bf16(a2, w2A0, D0, 0, 0, 0);
  D1 = __builtin_amdgcn_mfma_f32_16x16x32_bf16(a2, w2A1, D1, 0, 0, 0);
  D0 = __builtin_amdgcn_mfma_f32_16x16x32_bf16(a3, w2B0, D0, 0, 0, 0);
  D1 = __builtin_amdgcn_mfma_f32_16x16x32_bf16(a3, w2B1, D1, 0, 0, 0);

  // ---- LSE across the 16 col-lanes (4 rows per lane in D regs) ----
  float rowsum = 0.f;
#pragma unroll
  for (int j = 0; j < 4; ++j) {
    const float cc0 = D0[j] + As0;
    const float cc1 = D1[j] + As1;
    float m = fmaxf(cc0, cc1);
    m = fmaxf(m, __shfl_xor(m, 1));
    m = fmaxf(m, __shfl_xor(m, 2));
    m = fmaxf(m, __shfl_xor(m, 4));
    m = fmaxf(m, __shfl_xor(m, 8));
    float e = __expf(cc0 - m) + __expf(cc1 - m);
    e += __shfl_xor(e, 1);
    e += __shfl_xor(e, 2);
    e += __shfl_xor(e, 4);
    e += __shfl_xor(e, 8);
    const int rj = rowbase + g * 4 + j;  // D row = (lane>>4)*4 + reg
    rowsum += (rj < n) ? (m + __logf(e)) : 0.f;
  }
  float v = (c1 == 0) ? rowsum : 0.f;  // one lane per (g, row-quad)
  v += __shfl_xor(v, 16);
  v += __shfl_xor(v, 32);
  if (lane == 0) bred[wave] = v;
  __syncthreads();
  if (t == 0) ws[blockIdx.x] = (bred[0] + bred[1]) + (bred[2] + bred[3]);
}

// 1-block tail: sum per-block partials, scale, add all priors, overwrite out.
__global__ __launch_bounds__(256) void gmm_tail(const float* __restrict__ theta,
                                                const int* __restrict__ fds,
                                                const float* __restrict__ ws,
                                                float* __restrict__ out,
                                                int n, int nblk) {
  const int t = threadIdx.x;
  float acc = 0.f;
  for (int i = t; i < nblk; i += 256) acc += ws[i];
  acc *= (float)fds[0] / (float)n;
  const int k = t >> 3, jj = t & 7;
  float pr = 0.f;
#pragma unroll
  for (int i = 0; i < 8; ++i) {
    const int idx = k * GD + jj * 8 + i;
    const float mu = theta[GK + idx];
    const float sg = theta[GK + GK * GD + idx];
    const float ls = __logf(sg);
    pr += -0.5f * mu * mu - ls - 0.5f * ls * ls - LOG2PI_F;
  }
  if (jj == 0) pr += 999.0f * __logf(theta[k]);  // (ALPHA0-1)*log p
  acc += pr;
  __shared__ float red[256];
  red[t] = acc;
  __syncthreads();
  for (int off = 128; off > 0; off >>= 1) {
    if (t < off) red[t] += red[t + off];
    __syncthreads();
  }
  if (t == 0) {
    const double gterm = lgamma(32.0 * 1000.0) - 32.0 * lgamma(1000.0);
    out[0] = red[0] + (float)gterm;
  }
}
}  // namespace

extern "C" void kernel_launch(void* const* d_in, const int* in_sizes, int n_in,
                              void* d_out, int out_size, void* d_ws, size_t ws_size,
                              hipStream_t stream) {
  const float* x = (const float*)d_in[0];
  const float* theta = (const float*)d_in[1];
  const int* fds = (const int*)d_in[2];
  float* out = (float*)d_out;
  float* ws = (float*)d_ws;
  const int n = in_sizes[0] / GD;   // 50000
  const int nblk = (n + 63) / 64;   // 64 rows per block (4 waves x 16)

  gmm_main<<<nblk, 256, 0, stream>>>(x, theta, ws, n);
  gmm_tail<<<1, 256, 0, stream>>>(theta, fds, ws, out, n, nblk);
}